// Round 5
// baseline (30.272 us; speedup 1.0000x reference)
//
#include <hip/hip_runtime.h>

// Problem constants (fixed by the reference setup)
#define BB 8
#define LL 4096
#define DD 1024
#define KK 2048
#define RPB 8   // rows per gather block

typedef float f32x4 __attribute__((ext_vector_type(4)));

// One block (1024 threads = 16 waves) per batch.
// Stable compaction via hierarchical prefix scan:
//   boundary positions get rank = #boundaries before them;
//   non-boundary positions get rank = num_tokens + #non-boundaries before them.
// Scatter i -> idx[rank] for rank < K. Reproduces argsort(i + (~bm)*L)[:K]
// exactly (keys are unique). Also writes the next_mask output (fused).
__global__ void build_idx_kernel(const int* __restrict__ bm,
                                 int* __restrict__ idx,
                                 float* __restrict__ om) {
    __shared__ int wsum[16];
    const int b    = blockIdx.x;
    const int tid  = threadIdx.x;      // 0..1023
    const int lane = tid & 63;
    const int wave = tid >> 6;         // 0..15

    const int* m = bm + (size_t)b * LL;

    const int base = tid * 4;
    const int4 v = *reinterpret_cast<const int4*>(m + base);
    int local[4] = { v.x != 0, v.y != 0, v.z != 0, v.w != 0 };
    const int s = local[0] + local[1] + local[2] + local[3];

    // wave-level inclusive scan (no barriers)
    int incl = s;
#pragma unroll
    for (int off = 1; off < 64; off <<= 1) {
        const int t = __shfl_up(incl, off, 64);
        if (lane >= off) incl += t;
    }
    if (lane == 63) wsum[wave] = incl;
    __syncthreads();

    if (wave == 0) {
        int wv = (lane < 16) ? wsum[lane] : 0;
#pragma unroll
        for (int off = 1; off < 16; off <<= 1) {
            const int t = __shfl_up(wv, off, 64);
            if (lane >= off) wv += t;
        }
        if (lane < 16) wsum[lane] = wv;
    }
    __syncthreads();

    const int total   = wsum[15];                    // num_tokens for batch b
    const int waveoff = (wave == 0) ? 0 : wsum[wave - 1];
    int brank = waveoff + incl - s;                  // exclusive boundary rank

    int* ib = idx + (size_t)b * KK;
#pragma unroll
    for (int j = 0; j < 4; ++j) {
        const int i = base + j;
        if (local[j]) {
            if (brank < KK) ib[brank] = i;
            ++brank;
        } else {
            const int nr = total + (i - brank);
            if (nr < KK) ib[nr] = i;
        }
    }

    float* omb = om + (size_t)b * KK;
    omb[tid]        = (tid        < total) ? 1.0f : 0.0f;
    omb[tid + 1024] = (tid + 1024 < total) ? 1.0f : 0.0f;
}

// 8 rows per block, 256 threads. 8 uniform idx loads, then 8 independent
// row loads issued before any store (max MLP), NT stores (streaming output).
__global__ void __launch_bounds__(256)
gather8_kernel(const f32x4* __restrict__ src,
               const int* __restrict__ idx,
               f32x4* __restrict__ dst) {
    const int blk   = blockIdx.x;          // 0 .. 2047
    const int tid   = threadIdx.x;         // 0 .. 255
    const int b     = blk >> 8;            // 256 blocks per batch
    const int kbase = (blk & 255) * RPB;

    const int* ib = idx + (size_t)b * KK + kbase;
    int rows[RPB];
#pragma unroll
    for (int j = 0; j < RPB; ++j) rows[j] = ib[j];   // uniform -> scalar loads

    const f32x4* s = src + (size_t)b * LL * (DD / 4) + tid;
    f32x4*       d = dst + ((size_t)b * KK + kbase) * (DD / 4) + tid;

    f32x4 v[RPB];
#pragma unroll
    for (int j = 0; j < RPB; ++j)
        v[j] = s[(size_t)rows[j] * (DD / 4)];
#pragma unroll
    for (int j = 0; j < RPB; ++j)
        __builtin_nontemporal_store(v[j], &d[(size_t)j * (DD / 4)]);
}

extern "C" void kernel_launch(void* const* d_in, const int* in_sizes, int n_in,
                              void* d_out, int out_size, void* d_ws, size_t ws_size,
                              hipStream_t stream) {
    const float* hs = (const float*)d_in[0];   // (B, L, D) f32
    const int*   bm = (const int*)d_in[1];     // (B, L) bool -> int32
    // d_in[2] (mask) unused; d_in[3] (next_max_seqlen) fixed at K=2048

    float* out_hs   = (float*)d_out;                        // B*K*D floats
    float* out_mask = (float*)d_out + (size_t)BB * KK * DD; // B*K floats

    int* idx = (int*)d_ws;                 // B*K ints

    build_idx_kernel<<<BB, 1024, 0, stream>>>(bm, idx, out_mask);
    gather8_kernel<<<(BB * KK) / RPB, 256, 0, stream>>>(
        (const f32x4*)hs, idx, (f32x4*)out_hs);
}